// Round 1
// baseline (357.138 us; speedup 1.0000x reference)
//
#include <hip/hip_runtime.h>

// Problem constants: B=8, N=32, T=64, D=128, E=4, H=32, BT=512
#define LDB 132   // padded stride for 32x128 LDS tiles (128+4, breaks conflicts, keeps 16B align)
#define LDH 33    // padded stride for 32x32 tiles ([n][h] / logits)
#define LDHT 36   // padded stride for transposed hq ([h][n]), keeps float4 16B align

// Out[n][i] = sum_j A[n][j] * W[i][j], n in [0,32), i,j in [0,128)
// A: LDS (stride LDB). W: global row-major 128x128, staged transposed into Wt (16x LDB).
// Each thread computes a 4x4 tile: i0 = 4*(tid&31), n0 = 4*(tid>>5).
__device__ __forceinline__ void gemm_core(const float* __restrict__ A,
                                          const float* __restrict__ W,
                                          float* __restrict__ Wt,
                                          int tid, float acc[4][4])
{
    const int i0 = (tid & 31) * 4;
    const int n0 = (tid >> 5) * 4;
    for (int j0 = 0; j0 < 128; j0 += 16) {
        __syncthreads();   // previous tile's readers done / previous phase done
#pragma unroll
        for (int rr = 0; rr < 2; ++rr) {
            int flat = tid + rr * 256;     // 0..511
            int i = flat >> 2, c = flat & 3;
            float4 w = *(const float4*)(W + i * 128 + j0 + 4 * c);
            Wt[(4*c+0)*LDB + i] = w.x;
            Wt[(4*c+1)*LDB + i] = w.y;
            Wt[(4*c+2)*LDB + i] = w.z;
            Wt[(4*c+3)*LDB + i] = w.w;
        }
        __syncthreads();
#pragma unroll
        for (int jj = 0; jj < 16; jj += 4) {
            float4 w0 = *(const float4*)(Wt + (jj+0)*LDB + i0);
            float4 w1 = *(const float4*)(Wt + (jj+1)*LDB + i0);
            float4 w2 = *(const float4*)(Wt + (jj+2)*LDB + i0);
            float4 w3 = *(const float4*)(Wt + (jj+3)*LDB + i0);
#pragma unroll
            for (int r = 0; r < 4; ++r) {
                float4 z = *(const float4*)(A + (n0+r)*LDB + j0 + jj);
                acc[r][0] = fmaf(z.x, w0.x, fmaf(z.y, w1.x, fmaf(z.z, w2.x, fmaf(z.w, w3.x, acc[r][0]))));
                acc[r][1] = fmaf(z.x, w0.y, fmaf(z.y, w1.y, fmaf(z.z, w2.y, fmaf(z.w, w3.y, acc[r][1]))));
                acc[r][2] = fmaf(z.x, w0.z, fmaf(z.y, w1.z, fmaf(z.z, w2.z, fmaf(z.w, w3.z, acc[r][2]))));
                acc[r][3] = fmaf(z.x, w0.w, fmaf(z.y, w1.w, fmaf(z.z, w2.w, fmaf(z.w, w3.w, acc[r][3]))));
            }
        }
    }
    __syncthreads();   // compute done before Wt (U) is reused by caller
}

__device__ __forceinline__ void gemm_to_lds(const float* __restrict__ A,
                                            const float* __restrict__ W,
                                            float* __restrict__ Out,
                                            float* __restrict__ Wt, int tid)
{
    float acc[4][4];
#pragma unroll
    for (int r = 0; r < 4; ++r)
#pragma unroll
        for (int c = 0; c < 4; ++c) acc[r][c] = 0.f;
    gemm_core(A, W, Wt, tid, acc);
    const int i0 = (tid & 31) * 4;
    const int n0 = (tid >> 5) * 4;
#pragma unroll
    for (int r = 0; r < 4; ++r)
        *(float4*)(Out + (n0+r)*LDB + i0) = make_float4(acc[r][0], acc[r][1], acc[r][2], acc[r][3]);
    __syncthreads();
}

__global__ __launch_bounds__(256, 2)
void gnn_fused(const float* __restrict__ x,          // (B,N,T,D)
               const float* __restrict__ edge,       // (BT,N,N,E)
               const float* __restrict__ A_prior,    // (BT,N,N,5)
               const unsigned char* __restrict__ pad_mask, // (B,N) bool
               const float* __restrict__ Wq,         // (D,D)
               const float* __restrict__ Wk,
               const float* __restrict__ Wv,
               const float* __restrict__ Theta,
               const float* __restrict__ Wfuse,      // (1,5)
               const float* __restrict__ W1,         // (32,260)
               const float* __restrict__ b1,         // (32,)
               const float* __restrict__ W2,         // (1,32)
               const float* __restrict__ b2,         // (1,)
               const float* __restrict__ gma,        // (128,)
               const float* __restrict__ bta,        // (128,)
               const float* __restrict__ physw,
               const float* __restrict__ priorw,
               float* __restrict__ out)              // (B,N,T,D)
{
    __shared__ __align__(16) float Zs[32 * LDB];
    __shared__ __align__(16) float Qs[32 * LDB];   // Q, later V
    __shared__ __align__(16) float Ks[32 * LDB];   // K, later spatial
    __shared__ __align__(16) float U[2208];        // union: Wt[16*LDB] | {hq^T[32*LDHT], hk[32*LDH]}
    __shared__ __align__(16) float Lg[32 * LDH];   // logits -> alpha
    __shared__ __align__(16) float4 W1e_s[32];
    __shared__ float W2_s[32];
    __shared__ float Wf_s[5];
    __shared__ float maskrow[32];

    const int tid = threadIdx.x;
    const int bt  = blockIdx.x;       // 0..511
    const int b_  = bt >> 6;          // /64 (T)
    const int t_  = bt & 63;

    const float pw  = physw[0];
    const float rw  = priorw[0];
    const float b2v = b2[0];

    // ---- P0: stage Z[n][d] = x[b][n][t][d]; load small weights ----
#pragma unroll
    for (int q = 0; q < 4; ++q) {
        int f  = tid + 256 * q;        // 0..1023 float4 slots
        int n  = f >> 5;
        int d0 = (f & 31) * 4;
        float4 v = *(const float4*)(x + ((size_t)(b_ * 32 + n) * 64 + t_) * 128 + d0);
        *(float4*)(Zs + n * LDB + d0) = v;
    }
    if (tid < 32) {
        int h = tid;
        W1e_s[h] = *(const float4*)(W1 + h * 260 + 256);
        W2_s[h]  = W2[h];
        maskrow[h] = pad_mask[b_ * 32 + h] ? 1.f : 0.f;
        if (h < 5) Wf_s[h] = Wfuse[h];
    }
    // (gemm_core's leading __syncthreads covers P0 completion)

    // ---- P1: Q = Z @ Wq^T, K = Z @ Wk^T ----
    gemm_to_lds(Zs, Wq, Qs, U, tid);
    gemm_to_lds(Zs, Wk, Ks, U, tid);

    // ---- P2: hq = Q @ W1q^T + b1 (stored transposed [h][n]), hk = K @ W1k^T ([n][h]) ----
    {
        const int h = tid & 31, n4 = tid >> 5;
        const float* w1row = W1 + h * 260;
        const float b1v = b1[h];
        float accq[4] = {0,0,0,0}, acck[4] = {0,0,0,0};
        for (int j = 0; j < 128; j += 4) {
            float4 wq4 = *(const float4*)(w1row + j);
            float4 wk4 = *(const float4*)(w1row + 128 + j);
#pragma unroll
            for (int r = 0; r < 4; ++r) {
                float4 q4 = *(const float4*)(Qs + (4*n4+r)*LDB + j);
                float4 k4 = *(const float4*)(Ks + (4*n4+r)*LDB + j);
                accq[r] = fmaf(q4.x, wq4.x, fmaf(q4.y, wq4.y, fmaf(q4.z, wq4.z, fmaf(q4.w, wq4.w, accq[r]))));
                acck[r] = fmaf(k4.x, wk4.x, fmaf(k4.y, wk4.y, fmaf(k4.z, wk4.z, fmaf(k4.w, wk4.w, acck[r]))));
            }
        }
#pragma unroll
        for (int r = 0; r < 4; ++r) {
            int n = 4*n4 + r;
            U[h * LDHT + n]        = accq[r] + b1v;   // hq^T (b1 folded in)
            U[1152 + n * LDH + h]  = acck[r];         // hk
        }
    }
    __syncthreads();

    // ---- P3: logits = QK^T/sqrt(d) + pw*phys + rw*log(prior+1e-6), masked ----
    {
        const int m = tid & 31, n4 = tid >> 5;
        float accc[4] = {0,0,0,0};
        for (int j = 0; j < 128; j += 4) {
            float4 k4 = *(const float4*)(Ks + m * LDB + j);
#pragma unroll
            for (int r = 0; r < 4; ++r) {
                float4 q4 = *(const float4*)(Qs + (4*n4+r)*LDB + j);
                accc[r] = fmaf(q4.x, k4.x, fmaf(q4.y, k4.y, fmaf(q4.z, k4.z, fmaf(q4.w, k4.w, accc[r]))));
            }
        }
        float4 e4[4];
#pragma unroll
        for (int r = 0; r < 4; ++r)
            e4[r] = *(const float4*)(edge + (((size_t)bt * 32 + (4*n4+r)) * 32 + m) * 4);
        float pacc[4] = {0,0,0,0};
        for (int h = 0; h < 32; ++h) {
            float4 we  = W1e_s[h];
            float w2v  = W2_s[h];
            float hkv  = U[1152 + m * LDH + h];
            float4 hq4 = *(const float4*)(U + h * LDHT + 4*n4);
            float hqv[4] = {hq4.x, hq4.y, hq4.z, hq4.w};
#pragma unroll
            for (int r = 0; r < 4; ++r) {
                float he = fmaf(e4[r].x, we.x, fmaf(e4[r].y, we.y, fmaf(e4[r].z, we.z, e4[r].w * we.w)));
                float v  = hqv[r] + hkv + he;   // b1 already folded into hq
                pacc[r]  = fmaf(fmaxf(v, 0.f), w2v, pacc[r]);
            }
        }
#pragma unroll
        for (int r = 0; r < 4; ++r) {
            int n = 4*n4 + r;
            size_t pb = (((size_t)bt * 32 + n) * 32 + m) * 5;
            float pr = A_prior[pb]   * Wf_s[0] + A_prior[pb+1] * Wf_s[1]
                     + A_prior[pb+2] * Wf_s[2] + A_prior[pb+3] * Wf_s[3]
                     + A_prior[pb+4] * Wf_s[4];
            if (!(fabsf(pr) < 1e30f)) pr = 0.f;   // nan/inf -> 0
            pr = fmaxf(pr, 0.f);
            float lg = accc[r] * 0.08838834764831845f          // 1/sqrt(128)
                     + pw * (pacc[r] + b2v)
                     + rw * __logf(pr + 1e-6f);
            if (maskrow[n] != 0.f || maskrow[m] != 0.f) lg = -1e9f;
            Lg[n * LDH + m] = lg;
        }
    }
    __syncthreads();

    // ---- P4: row softmax over m (32 threads, one per row) ----
    if (tid < 32) {
        const int n = tid;
        float mx = -3.4e38f;
        for (int m2 = 0; m2 < 32; ++m2) mx = fmaxf(mx, Lg[n * LDH + m2]);
        float s = 0.f;
        for (int m2 = 0; m2 < 32; ++m2) {
            float e = __expf(Lg[n * LDH + m2] - mx);
            Lg[n * LDH + m2] = e;
            s += e;
        }
        float inv = 1.f / s;
        for (int m2 = 0; m2 < 32; ++m2) Lg[n * LDH + m2] *= inv;
    }
    __syncthreads();

    // ---- P5: V = Z @ Wv^T (into Qs; Q is dead) ----
    gemm_to_lds(Zs, Wv, Qs, U, tid);

    // ---- P6: spatial = alpha @ V (into Ks; K is dead) ----
    {
        const int d0 = (tid & 31) * 4;
        const int n0 = (tid >> 5) * 4;
        float sa[4][4];
#pragma unroll
        for (int r = 0; r < 4; ++r)
#pragma unroll
            for (int c = 0; c < 4; ++c) sa[r][c] = 0.f;
        for (int m = 0; m < 32; ++m) {
            float4 v4 = *(const float4*)(Qs + m * LDB + d0);
            float a0 = Lg[(n0+0)*LDH + m];
            float a1 = Lg[(n0+1)*LDH + m];
            float a2 = Lg[(n0+2)*LDH + m];
            float a3 = Lg[(n0+3)*LDH + m];
            sa[0][0] = fmaf(a0, v4.x, sa[0][0]); sa[0][1] = fmaf(a0, v4.y, sa[0][1]);
            sa[0][2] = fmaf(a0, v4.z, sa[0][2]); sa[0][3] = fmaf(a0, v4.w, sa[0][3]);
            sa[1][0] = fmaf(a1, v4.x, sa[1][0]); sa[1][1] = fmaf(a1, v4.y, sa[1][1]);
            sa[1][2] = fmaf(a1, v4.z, sa[1][2]); sa[1][3] = fmaf(a1, v4.w, sa[1][3]);
            sa[2][0] = fmaf(a2, v4.x, sa[2][0]); sa[2][1] = fmaf(a2, v4.y, sa[2][1]);
            sa[2][2] = fmaf(a2, v4.z, sa[2][2]); sa[2][3] = fmaf(a2, v4.w, sa[2][3]);
            sa[3][0] = fmaf(a3, v4.x, sa[3][0]); sa[3][1] = fmaf(a3, v4.y, sa[3][1]);
            sa[3][2] = fmaf(a3, v4.z, sa[3][2]); sa[3][3] = fmaf(a3, v4.w, sa[3][3]);
        }
#pragma unroll
        for (int r = 0; r < 4; ++r)
            *(float4*)(Ks + (n0+r)*LDB + d0) = make_float4(sa[r][0], sa[r][1], sa[r][2], sa[r][3]);
    }
    // (gemm_core's leading __syncthreads covers P6 completion)

    // ---- P7: y = Z + spatial @ Theta^T; LayerNorm; store transposed ----
    {
        float acc[4][4];
#pragma unroll
        for (int r = 0; r < 4; ++r)
#pragma unroll
            for (int c = 0; c < 4; ++c) acc[r][c] = 0.f;
        gemm_core(Ks, Theta, U, tid, acc);
        const int d0 = (tid & 31) * 4;
        const int n0 = (tid >> 5) * 4;
        float4 g4  = *(const float4*)(gma + d0);
        float4 be4 = *(const float4*)(bta + d0);
#pragma unroll
        for (int r = 0; r < 4; ++r) {
            const int n = n0 + r;
            float4 z = *(const float4*)(Zs + n * LDB + d0);
            float y0 = acc[r][0] + z.x;
            float y1 = acc[r][1] + z.y;
            float y2 = acc[r][2] + z.z;
            float y3 = acc[r][3] + z.w;
            float s  = y0 + y1 + y2 + y3;
            float s2 = y0*y0 + y1*y1 + y2*y2 + y3*y3;
            // row n lives on 32 lanes (lanes 0..31 / 32..63 of a wave share n)
#pragma unroll
            for (int off = 1; off < 32; off <<= 1) {
                s  += __shfl_xor(s,  off, 64);
                s2 += __shfl_xor(s2, off, 64);
            }
            float mu   = s * 0.0078125f;               // /128
            float var  = s2 * 0.0078125f - mu * mu;
            float rstd = rsqrtf(var + 1e-5f);
            float4 o;
            o.x = (y0 - mu) * rstd * g4.x + be4.x;
            o.y = (y1 - mu) * rstd * g4.y + be4.y;
            o.z = (y2 - mu) * rstd * g4.z + be4.z;
            o.w = (y3 - mu) * rstd * g4.w + be4.w;
            if (maskrow[n] != 0.f) { o.x = 0.f; o.y = 0.f; o.z = 0.f; o.w = 0.f; }
            *(float4*)(out + ((size_t)(b_ * 32 + n) * 64 + t_) * 128 + d0) = o;
        }
    }
}

extern "C" void kernel_launch(void* const* d_in, const int* in_sizes, int n_in,
                              void* d_out, int out_size, void* d_ws, size_t ws_size,
                              hipStream_t stream) {
    const float* x        = (const float*)d_in[0];
    const float* edge     = (const float*)d_in[1];
    const float* A_prior  = (const float*)d_in[2];
    const unsigned char* pad_mask = (const unsigned char*)d_in[3];
    const float* Wq       = (const float*)d_in[4];
    const float* Wk       = (const float*)d_in[5];
    const float* Wv       = (const float*)d_in[6];
    const float* Theta    = (const float*)d_in[7];
    const float* Wfuse    = (const float*)d_in[8];
    const float* W1       = (const float*)d_in[9];
    const float* b1       = (const float*)d_in[10];
    const float* W2       = (const float*)d_in[11];
    const float* b2       = (const float*)d_in[12];
    const float* gma      = (const float*)d_in[13];
    const float* bta      = (const float*)d_in[14];
    const float* physw    = (const float*)d_in[15];
    const float* priorw   = (const float*)d_in[16];
    float* out = (float*)d_out;

    gnn_fused<<<dim3(512), dim3(256), 0, stream>>>(
        x, edge, A_prior, pad_mask, Wq, Wk, Wv, Theta, Wfuse,
        W1, b1, W2, b2, gma, bta, physw, priorw, out);
}